// Round 1
// 255.698 us; speedup vs baseline: 1.0467x; 1.0467x over previous
//
#include <hip/hip_runtime.h>
#include <hip/hip_bf16.h>

typedef __attribute__((ext_vector_type(8))) short bf16x8;
typedef __attribute__((ext_vector_type(4))) float f32x4;
typedef __attribute__((ext_vector_type(8))) unsigned short u16x8;

__device__ __forceinline__ unsigned short f2bf(float f) {
  union { float f; unsigned u; } c; c.f = f;
  unsigned u = c.u;
  u = (u + 0x7FFFu + ((u >> 16) & 1u)) >> 16;   // RNE
  return (unsigned short)u;
}

__device__ __forceinline__ void gld_lds16(const void* g, void* l) {
  __builtin_amdgcn_global_load_lds(
      (__attribute__((address_space(1))) unsigned int*)g,
      (__attribute__((address_space(3))) unsigned int*)l,
      16, 0, 0);
}

// ---------------- single fused conversion kernel (unchanged) ----------------
__global__ void cvt_all(const float* __restrict__ x, unsigned short* __restrict__ x16,
                        const float* __restrict__ Kw, unsigned short* __restrict__ K16,
                        const float* __restrict__ V, unsigned short* __restrict__ Vt,
                        float* __restrict__ lsum) {
  const int b = blockIdx.x;
  if (b < 32) lsum[b * 256 + threadIdx.x] = 0.f;

  if (b < 6144) {
    const float* in;
    unsigned short* out;
    int i;
    if (b < 4096) {
      in = x; out = x16; i = (b * 256 + threadIdx.x) * 8;
    } else {
      in = Kw; out = K16; i = ((b - 4096) * 256 + threadIdx.x) * 8;
    }
    const float4* p = (const float4*)(in + i);
    float4 a = p[0], bb = p[1];
    u16x8 r;
    r[0] = f2bf(a.x); r[1] = f2bf(a.y); r[2] = f2bf(a.z); r[3] = f2bf(a.w);
    r[4] = f2bf(bb.x); r[5] = f2bf(bb.y); r[6] = f2bf(bb.z); r[7] = f2bf(bb.w);
    *(u16x8*)(out + i) = r;
  } else {
    __shared__ unsigned short t[64][65];
    const int tile = b - 6144;
    const int p0 = (tile & 63) * 64;
    const int e0 = (tile >> 6) * 64;
    const int tx = threadIdx.x & 63;
    const int ty = threadIdx.x >> 6;
#pragma unroll
    for (int i = 0; i < 16; ++i) {
      int p = ty + i * 4;
      t[p][tx] = f2bf(V[(size_t)(p0 + p) * 1024 + e0 + tx]);
    }
    __syncthreads();
#pragma unroll
    for (int i = 0; i < 16; ++i) {
      int e = ty + i * 4;
      Vt[(size_t)(e0 + e) * 4096 + p0 + tx] = t[tx][e];
    }
  }
}

// ---------------- 8-phase deep-pipelined NT GEMM (m201-style template) ------
// A [M x Kd], B [N x Kd] row-major bf16 (NT layout). S = A.B^T.
// EPI==0: BM=256,BN=256, grid 512 (32m x 16n). P = exp2(scale*S) -> Pout bf16,
//         row sums atomically into lsum.
// EPI==1: BM=128,BN=256, grid 256 (64m x 4n).  C = S / lin[row] -> Cout fp32.
//
// Schedule (per K-tile group g, PH phases, 2 barriers/phase):
//   phase p: { ds_read frags (B all at p0, A-pair at each p) |
//              issue 1-2 global_load_lds staging units |
//              s_barrier ; lgkmcnt(0)+sched_barrier ; setprio(1) 16xMFMA
//              setprio(0) ; [group end: vmcnt(4)] ; s_barrier }
// Staging: A-units of tile g+1 at early phases, B-units of tile g+2 at late
// phases. vmcnt(4) at group end drains tile g+1 fully, leaves B(g+2) (2 units,
// 4 loads/thread) in flight. WAR safety: a unit's overwrite issue is separated
// from its last ds_read by a full barrier+lgkmcnt round (BAR2 semantics).
// Tail: staged tiles wrap modulo NT (dummy, never consumed, in-bounds).
template <int EPI>
__global__ __launch_bounds__(512, 2) void gemm8p(
    const unsigned short* __restrict__ A, const unsigned short* __restrict__ B,
    unsigned short* __restrict__ Pout, float* __restrict__ lsum,
    float* __restrict__ Cout, const float* __restrict__ lin, float scale) {
  constexpr int BM = EPI ? 128 : 256;
  constexpr int BN = 256;
  constexpr int Kd = EPI ? 4096 : 1024;
  constexpr int Nc = EPI ? 1024 : 4096;   // C columns == B row count
  constexpr int NT = Kd / 64;             // K-tiles (16 / 64), pow2
  constexpr int AU = BM / 128;            // A 16KB units per tile (2 / 1)
  constexpr int NU = AU + 2;              // + 2 B units
  constexpr int M_rep = BM / 32;          // per-wave m fragments (8 / 4)
  constexpr int PH = M_rep / 2;           // phases per K-tile (4 / 2)

  __shared__ __align__(16) char lds[2 * NU * 16384];   // 128 KB / 96 KB

  const int tid = threadIdx.x;
  const int lane = tid & 63;
  const int w = tid >> 6;        // 8 waves
  const int wm = w >> 2;         // 0..1
  const int wn = w & 3;          // 0..3
  const int q = lane >> 4;       // 0..3
  const int ml = lane & 15;

  // XCD-swizzled block -> tile (grid % 8 == 0, bijective)
  const int bid = blockIdx.x;
  const int wg = (bid & 7) * (EPI ? 32 : 64) + (bid >> 3);
  const int m_t = EPI ? (wg >> 2) : (wg >> 4);
  const int n_t = EPI ? (wg & 3) : (wg & 15);
  const int row0 = m_t * BM;
  const int col0 = n_t * BN;

  // Staging addressing: LDS linear (wave-uniform base + lane*16), global
  // source pre-swizzled: chunk c -> row r=c>>3, lds slot s=c&7 holds global
  // k-chunk s^(r&7). Each thread stages chunks tid and tid+512 per unit.
  const int cr = tid >> 3;                       // 0..63 (+64 for 2nd chunk)
  const int ss = (tid & 7) ^ (cr & 7);           // swizzled source k-chunk
  char* ldsw = lds + w * 1024 + lane * 16;

  // Fragment read offsets (XOR-swizzled): within-unit byte address
  //   row_in_unit*128 + ((ks*4+q)^(ml&7))*16, with ks folding to ^64.
  const int ccB = (q ^ (ml & 7)) * 16;
  const int aOff = (EPI ? 0 : wm) * 16384 + ((EPI ? wm * 64 : 0) + ml) * 128 + ccB;
  const int bOff = (AU + (wn >> 1)) * 16384 + ((wn & 1) * 64 + ml) * 128 + ccB;

  f32x4 acc[M_rep][4] = {};
  bf16x8 bF[4][2];   // [ni][ks], loaded at phase 0, live across the group

  auto stA = [&](int a, int t, int buf) {
    const unsigned short* s = A + (size_t)(row0 + a * 128 + cr) * Kd + t * 64 + ss * 8;
    char* d = ldsw + (buf * NU + a) * 16384;
    gld_lds16(s, d);
    gld_lds16(s + (size_t)64 * Kd, d + 8192);
  };
  auto stB = [&](int b, int t, int buf) {
    const unsigned short* s = B + (size_t)(col0 + b * 128 + cr) * Kd + t * 64 + ss * 8;
    char* d = ldsw + (buf * NU + AU + b) * 16384;
    gld_lds16(s, d);
    gld_lds16(s + (size_t)64 * Kd, d + 8192);
  };

  // Prologue: tile 0 (all units) + tile 1 B-units; drain tile 0, keep B(1)
  // in flight (vmcnt(4)).
#pragma unroll
  for (int a = 0; a < AU; ++a) stA(a, 0, 0);
  stB(0, 0, 0); stB(1, 0, 0);
  stB(0, 1, 1); stB(1, 1, 1);
  asm volatile("s_waitcnt vmcnt(4)" ::: "memory");
  __builtin_amdgcn_s_barrier();

#pragma unroll 2
  for (int g = 0; g < NT; ++g) {
    const char* base = lds + (g & 1) * (NU * 16384);
    const int tA = (g + 1) & (NT - 1);
    const int bufA = (g + 1) & 1;
    const int tB = (g + 2) & (NT - 1);
    const int bufB = g & 1;
#pragma unroll
    for (int p = 0; p < PH; ++p) {
      if (p == 0) {
#pragma unroll
        for (int ni = 0; ni < 4; ++ni)
#pragma unroll
          for (int ks = 0; ks < 2; ++ks)
            bF[ni][ks] = *(const bf16x8*)(base + ((bOff ^ (ks * 64)) + ni * 2048));
      }
      bf16x8 aF[2][2];
#pragma unroll
      for (int i = 0; i < 2; ++i)
#pragma unroll
        for (int ks = 0; ks < 2; ++ks)
          aF[i][ks] = *(const bf16x8*)(base + ((aOff ^ (ks * 64)) + (2 * p + i) * 2048));

      // staging schedule
      if constexpr (EPI == 0) {
        if (p == 0) stA(0, tA, bufA);
        else if (p == 1) stA(1, tA, bufA);
        else if (p == 2) stB(0, tB, bufB);
        else stB(1, tB, bufB);
      } else {
        if (p == 0) stA(0, tA, bufA);
        else { stB(0, tB, bufB); stB(1, tB, bufB); }
      }

      __builtin_amdgcn_s_barrier();
      asm volatile("s_waitcnt lgkmcnt(0)" ::: "memory");
      __builtin_amdgcn_sched_barrier(0);
      __builtin_amdgcn_s_setprio(1);
#pragma unroll
      for (int ks = 0; ks < 2; ++ks)
#pragma unroll
        for (int i = 0; i < 2; ++i)
#pragma unroll
          for (int ni = 0; ni < 4; ++ni)
            acc[2 * p + i][ni] = __builtin_amdgcn_mfma_f32_16x16x32_bf16(
                aF[i][ks], bF[ni][ks], acc[2 * p + i][ni], 0, 0, 0);
      __builtin_amdgcn_s_setprio(0);
      if (p == PH - 1) asm volatile("s_waitcnt vmcnt(4)" ::: "memory");
      __builtin_amdgcn_s_barrier();
    }
  }

  if constexpr (EPI == 0) {
#pragma unroll
    for (int mi = 0; mi < M_rep; ++mi) {
#pragma unroll
      for (int j = 0; j < 4; ++j) {
        const int gr = row0 + wm * (BM / 2) + mi * 16 + q * 4 + j;
        float rsum = 0.f;
#pragma unroll
        for (int ni = 0; ni < 4; ++ni) {
          const int gc = col0 + wn * 64 + ni * 16 + ml;
          float pv = exp2f(acc[mi][ni][j] * scale);  // scale includes log2(e)
          rsum += pv;
          Pout[(size_t)gr * Nc + gc] = f2bf(pv);
        }
        rsum += __shfl_xor(rsum, 1);
        rsum += __shfl_xor(rsum, 2);
        rsum += __shfl_xor(rsum, 4);
        rsum += __shfl_xor(rsum, 8);
        if (ml == 0) atomicAdd(&lsum[gr], rsum);
      }
    }
  } else {
#pragma unroll
    for (int mi = 0; mi < M_rep; ++mi) {
#pragma unroll
      for (int j = 0; j < 4; ++j) {
        const int gr = row0 + wm * (BM / 2) + mi * 16 + q * 4 + j;
        const float rl = 1.0f / lin[gr];
#pragma unroll
        for (int ni = 0; ni < 4; ++ni) {
          const int gc = col0 + wn * 64 + ni * 16 + ml;
          Cout[(size_t)gr * Nc + gc] = acc[mi][ni][j] * rl;
        }
      }
    }
  }
}

extern "C" void kernel_launch(void* const* d_in, const int* in_sizes, int n_in,
                              void* d_out, int out_size, void* d_ws,
                              size_t ws_size, hipStream_t stream) {
  const float* x = (const float*)d_in[0];   // [8192,1024]
  const float* Kw = (const float*)d_in[1];  // [4096,1024]
  const float* Vw = (const float*)d_in[2];  // [4096,1024]
  float* out = (float*)d_out;               // [8192,1024]
  char* ws = (char*)d_ws;

  unsigned short* x16  = (unsigned short*)(ws);                   // 16 MB
  unsigned short* K16  = (unsigned short*)(ws + (16u << 20));     //  8 MB
  unsigned short* V16t = (unsigned short*)(ws + (24u << 20));     //  8 MB
  float*          lsum = (float*)(ws + (32u << 20));              // 32 KB
  unsigned short* P16  = (unsigned short*)(ws + (33u << 20));     // 64 MB

  cvt_all<<<7168, 256, 0, stream>>>(x, x16, Kw, K16, Vw, V16t, lsum);

  // GEMM1: P = exp(x16 . K16^T / 32), row sums -> lsum.
  gemm8p<0><<<512, 512, 0, stream>>>(
      x16, K16, P16, lsum, nullptr, nullptr,
      0.03125f * 1.44269504088896340736f);
  // GEMM2: out = (P16 . V16t^T) / lsum[row]
  gemm8p<1><<<256, 512, 0, stream>>>(
      P16, V16t, nullptr, nullptr, out, lsum, 0.f);
}

// Round 2
// 251.121 us; speedup vs baseline: 1.0658x; 1.0182x over previous
//
#include <hip/hip_runtime.h>
#include <hip/hip_bf16.h>

typedef __attribute__((ext_vector_type(8))) short bf16x8;
typedef __attribute__((ext_vector_type(4))) float f32x4;
typedef __attribute__((ext_vector_type(8))) unsigned short u16x8;

__device__ __forceinline__ unsigned short f2bf(float f) {
  union { float f; unsigned u; } c; c.f = f;
  unsigned u = c.u;
  u = (u + 0x7FFFu + ((u >> 16) & 1u)) >> 16;   // RNE
  return (unsigned short)u;
}

__device__ __forceinline__ void gld_lds16(const void* g, void* l) {
  __builtin_amdgcn_global_load_lds(
      (__attribute__((address_space(1))) unsigned int*)g,
      (__attribute__((address_space(3))) unsigned int*)l,
      16, 0, 0);
}

// ---------------- single fused conversion kernel ----------------
__global__ void cvt_all(const float* __restrict__ x, unsigned short* __restrict__ x16,
                        const float* __restrict__ Kw, unsigned short* __restrict__ K16,
                        const float* __restrict__ V, unsigned short* __restrict__ Vt,
                        float* __restrict__ lsum) {
  const int b = blockIdx.x;
  const int tid = threadIdx.x;
  if (b < 32) lsum[b * 256 + tid] = 0.f;

  if (b < 6144) {
    const float* in;
    unsigned short* out;
    int i;
    if (b < 4096) {
      in = x; out = x16; i = (b * 256 + tid) * 8;
    } else {
      in = Kw; out = K16; i = ((b - 4096) * 256 + tid) * 8;
    }
    const float4* p = (const float4*)(in + i);
    float4 a = p[0], bb = p[1];
    u16x8 r;
    r[0] = f2bf(a.x); r[1] = f2bf(a.y); r[2] = f2bf(a.z); r[3] = f2bf(a.w);
    r[4] = f2bf(bb.x); r[5] = f2bf(bb.y); r[6] = f2bf(bb.z); r[7] = f2bf(bb.w);
    *(u16x8*)(out + i) = r;
  } else {
    __shared__ unsigned short t[64][65];
    const int tile = b - 6144;
    const int p0 = (tile & 63) * 64;
    const int e0 = (tile >> 6) * 64;
    const int tx = tid & 63;
    const int ty = tid >> 6;
#pragma unroll
    for (int i = 0; i < 16; ++i) {
      int p = ty + i * 4;
      t[p][tx] = f2bf(V[(size_t)(p0 + p) * 1024 + e0 + tx]);
    }
    __syncthreads();
    // vectorized transposed store: each thread emits 2x 16B rows-octets
    const int op = (tid & 7) * 8;
    const int oe = tid >> 3;   // 0..31
#pragma unroll
    for (int h = 0; h < 2; ++h) {
      int e = oe + h * 32;
      u16x8 r;
#pragma unroll
      for (int i = 0; i < 8; ++i) r[i] = t[op + i][e];
      *(u16x8*)(Vt + (size_t)(e0 + e) * 4096 + p0 + op) = r;
    }
  }
}

// ------- deep-pipelined NT GEMM: counted lgkmcnt, reg-level A double-buffer -
// A [M x Kd], B [N x Kd] row-major bf16. S = A.B^T.
// EPI==0: BM=256,BN=256, grid 512. P = exp2(scale*S) -> Pout bf16 + row sums.
// EPI==1: BM=128,BN=256, grid 256. C = S / lin[row] -> Cout fp32.
//
// Slot structure (2 barriers/slot): issue next-phase ds_reads + staging ->
// barrier -> lgkmcnt(4) (counted: only the prefetch stays in flight) ->
// MFMA(current regs) -> barrier. vmcnt(4) once per tile, one slot before the
// next-buffer fragment reads. B-frags read once per tile (p0), held in regs.
template <int EPI>
__global__ __launch_bounds__(512, 2) void gemm8p(
    const unsigned short* __restrict__ A, const unsigned short* __restrict__ B,
    unsigned short* __restrict__ Pout, float* __restrict__ lsum,
    float* __restrict__ Cout, const float* __restrict__ lin, float scale) {
  constexpr int BM = EPI ? 128 : 256;
  constexpr int Kd = EPI ? 4096 : 1024;
  constexpr int Nc = EPI ? 1024 : 4096;
  constexpr int NT = Kd / 64;             // 16 / 64 K-tiles (pow2)
  constexpr int AU = BM / 128;            // A 16KB units per tile (2 / 1)
  constexpr int NU = AU + 2;              // + 2 B units
  constexpr int M_rep = BM / 32;          // 8 / 4

  __shared__ __align__(16) char lds[2 * NU * 16384];   // 128 / 96 KB

  const int tid = threadIdx.x;
  const int lane = tid & 63;
  const int w = tid >> 6;
  const int wm = w >> 2;
  const int wn = w & 3;
  const int q = lane >> 4;
  const int ml = lane & 15;

  const int bid = blockIdx.x;
  const int wg = (bid & 7) * (EPI ? 32 : 64) + (bid >> 3);
  const int m_t = EPI ? (wg >> 2) : (wg >> 4);
  const int n_t = EPI ? (wg & 3) : (wg & 15);
  const int row0 = m_t * BM;
  const int col0 = n_t * 256;

  // staging: chunk c -> row r=c>>3; LDS slot s=c&7 holds global k-chunk
  // s^(r&7). LDS dest is wave-uniform (HW adds lane*16).
  const int cr = tid >> 3;
  const int ss = (tid & 7) ^ (cr & 7);
  char* ldsw = lds + w * 1024;

  const int ccB = (q ^ (ml & 7)) * 16;
  const int aOff = (EPI ? 0 : wm) * 16384 + ((EPI ? wm * 64 : 0) + ml) * 128 + ccB;
  const int bOff = (AU + (wn >> 1)) * 16384 + ((wn & 1) * 64 + ml) * 128 + ccB;

  f32x4 acc[M_rep][4] = {};
  bf16x8 bF[4][2];        // current tile's B frags (held)
  bf16x8 aF[2][2][2];     // [parity][i][ks] A frag double-buffer

  auto stA = [&](int a, int t, int buf) {
    const unsigned short* s = A + (size_t)(row0 + a * 128 + cr) * Kd + t * 64 + ss * 8;
    char* d = ldsw + (buf * NU + a) * 16384;
    gld_lds16(s, d);
    gld_lds16(s + (size_t)64 * Kd, d + 8192);
  };
  auto stB = [&](int b, int t, int buf) {
    const unsigned short* s = B + (size_t)(col0 + b * 128 + cr) * Kd + t * 64 + ss * 8;
    char* d = ldsw + (buf * NU + AU + b) * 16384;
    gld_lds16(s, d);
    gld_lds16(s + (size_t)64 * Kd, d + 8192);
  };

  auto ldA = [&](int par, const char* bs, int ph) {
#pragma unroll
    for (int i = 0; i < 2; ++i)
#pragma unroll
      for (int ks = 0; ks < 2; ++ks)
        aF[par][i][ks] = *(const bf16x8*)(bs + (aOff ^ (ks * 64)) + (2 * ph + i) * 2048);
  };
  auto mf = [&](int p, bf16x8 (&af)[2][2]) {
#pragma unroll
    for (int ks = 0; ks < 2; ++ks)
#pragma unroll
      for (int i = 0; i < 2; ++i)
#pragma unroll
        for (int ni = 0; ni < 4; ++ni)
          acc[2 * p + i][ni] = __builtin_amdgcn_mfma_f32_16x16x32_bf16(
              af[i][ks], bF[ni][ks], acc[2 * p + i][ni], 0, 0, 0);
  };

  // Prologue: stage tile0 fully + B(1); drain tile0, keep B(1) in flight.
#pragma unroll
  for (int a = 0; a < AU; ++a) stA(a, 0, 0);
  stB(0, 0, 0); stB(1, 0, 0);
  stB(0, 1, 1); stB(1, 1, 1);
  asm volatile("s_waitcnt vmcnt(4)" ::: "memory");
  __builtin_amdgcn_s_barrier();
  __builtin_amdgcn_sched_barrier(0);
  ldA(0, lds, 0);   // tile0 phase0 frags

#pragma unroll 2
  for (int g = 0; g < NT; ++g) {
    const char* base = lds + (g & 1) * (NU * 16384);
    const char* baseN = lds + ((g + 1) & 1) * (NU * 16384);
    const int tA = (g + 1) & (NT - 1);
    const int bufA = (g + 1) & 1;
    const int tB = (g + 2) & (NT - 1);
    const int bufB = g & 1;

    // ---------- phase 0 ----------
#pragma unroll
    for (int ni = 0; ni < 4; ++ni)
#pragma unroll
      for (int ks = 0; ks < 2; ++ks)
        bF[ni][ks] = *(const bf16x8*)(base + (bOff ^ (ks * 64)) + ni * 2048);
    __builtin_amdgcn_sched_barrier(0);   // keep bF reads older than aF prefetch
    ldA(1, base, 1);
    stA(0, tA, bufA);
    if constexpr (EPI == 0) stA(1, tA, bufA);
    __builtin_amdgcn_sched_barrier(0);
    __builtin_amdgcn_s_barrier();
    asm volatile("s_waitcnt lgkmcnt(4)" ::: "memory");
    __builtin_amdgcn_sched_barrier(0);
    __builtin_amdgcn_s_setprio(1);
    mf(0, aF[0]);
    __builtin_amdgcn_s_setprio(0);
    __builtin_amdgcn_s_barrier();

    if constexpr (EPI == 0) {
      // ---------- phase 1 ----------
      ldA(0, base, 2);
      stB(0, tB, bufB);
      __builtin_amdgcn_sched_barrier(0);
      __builtin_amdgcn_s_barrier();
      asm volatile("s_waitcnt lgkmcnt(4)" ::: "memory");
      __builtin_amdgcn_sched_barrier(0);
      __builtin_amdgcn_s_setprio(1);
      mf(1, aF[1]);
      __builtin_amdgcn_s_setprio(0);
      __builtin_amdgcn_s_barrier();

      // ---------- phase 2 ----------
      ldA(1, base, 3);
      stB(1, tB, bufB);
      __builtin_amdgcn_sched_barrier(0);
      __builtin_amdgcn_s_barrier();
      asm volatile("s_waitcnt lgkmcnt(4)" ::: "memory");
      __builtin_amdgcn_sched_barrier(0);
      __builtin_amdgcn_s_setprio(1);
      mf(2, aF[0]);
      __builtin_amdgcn_s_setprio(0);
      asm volatile("s_waitcnt vmcnt(4)" ::: "memory");  // buffer g+1 staged
      __builtin_amdgcn_s_barrier();
      __builtin_amdgcn_sched_barrier(0);                // validity point

      // ---------- phase 3 ----------
      ldA(0, baseN, 0);   // next tile's phase-0 frags
      __builtin_amdgcn_sched_barrier(0);
      __builtin_amdgcn_s_barrier();
      asm volatile("s_waitcnt lgkmcnt(4)" ::: "memory");
      __builtin_amdgcn_sched_barrier(0);
      __builtin_amdgcn_s_setprio(1);
      mf(3, aF[1]);
      __builtin_amdgcn_s_setprio(0);
      __builtin_amdgcn_s_barrier();
    } else {
      // ---------- phase 1 (PH=2) ----------
      stB(0, tB, bufB);
      stB(1, tB, bufB);
      asm volatile("s_waitcnt vmcnt(4)" ::: "memory");  // buffer g+1 staged
      __builtin_amdgcn_s_barrier();
      __builtin_amdgcn_sched_barrier(0);                // validity point
      ldA(0, baseN, 0);   // next tile's phase-0 frags
      asm volatile("s_waitcnt lgkmcnt(4)" ::: "memory");
      __builtin_amdgcn_sched_barrier(0);
      __builtin_amdgcn_s_setprio(1);
      mf(1, aF[1]);
      __builtin_amdgcn_s_setprio(0);
      __builtin_amdgcn_s_barrier();
    }
  }

  if constexpr (EPI == 0) {
#pragma unroll
    for (int mi = 0; mi < M_rep; ++mi) {
#pragma unroll
      for (int j = 0; j < 4; ++j) {
        const int gr = row0 + wm * (BM / 2) + mi * 16 + q * 4 + j;
        float rsum = 0.f;
#pragma unroll
        for (int ni = 0; ni < 4; ++ni) {
          const int gc = col0 + wn * 64 + ni * 16 + ml;
          float pv = exp2f(acc[mi][ni][j] * scale);  // scale includes log2(e)
          rsum += pv;
          Pout[(size_t)gr * Nc + gc] = f2bf(pv);
        }
        rsum += __shfl_xor(rsum, 1);
        rsum += __shfl_xor(rsum, 2);
        rsum += __shfl_xor(rsum, 4);
        rsum += __shfl_xor(rsum, 8);
        if (ml == 0) atomicAdd(&lsum[gr], rsum);
      }
    }
  } else {
#pragma unroll
    for (int mi = 0; mi < M_rep; ++mi) {
#pragma unroll
      for (int j = 0; j < 4; ++j) {
        const int gr = row0 + wm * (BM / 2) + mi * 16 + q * 4 + j;
        const float rl = 1.0f / lin[gr];
#pragma unroll
        for (int ni = 0; ni < 4; ++ni) {
          const int gc = col0 + wn * 64 + ni * 16 + ml;
          Cout[(size_t)gr * Nc + gc] = acc[mi][ni][j] * rl;
        }
      }
    }
  }
}

extern "C" void kernel_launch(void* const* d_in, const int* in_sizes, int n_in,
                              void* d_out, int out_size, void* d_ws,
                              size_t ws_size, hipStream_t stream) {
  const float* x = (const float*)d_in[0];   // [8192,1024]
  const float* Kw = (const float*)d_in[1];  // [4096,1024]
  const float* Vw = (const float*)d_in[2];  // [4096,1024]
  float* out = (float*)d_out;               // [8192,1024]
  char* ws = (char*)d_ws;

  unsigned short* x16  = (unsigned short*)(ws);                   // 16 MB
  unsigned short* K16  = (unsigned short*)(ws + (16u << 20));     //  8 MB
  unsigned short* V16t = (unsigned short*)(ws + (24u << 20));     //  8 MB
  float*          lsum = (float*)(ws + (32u << 20));              // 32 KB
  unsigned short* P16  = (unsigned short*)(ws + (33u << 20));     // 64 MB

  cvt_all<<<7168, 256, 0, stream>>>(x, x16, Kw, K16, Vw, V16t, lsum);

  // GEMM1: P = exp(x16 . K16^T / 32), row sums -> lsum.
  gemm8p<0><<<512, 512, 0, stream>>>(
      x16, K16, P16, lsum, nullptr, nullptr,
      0.03125f * 1.44269504088896340736f);
  // GEMM2: out = (P16 . V16t^T) / lsum[row]
  gemm8p<1><<<256, 512, 0, stream>>>(
      P16, V16t, nullptr, nullptr, out, lsum, 0.f);
}